// Round 20
// baseline (207.585 us; speedup 1.0000x reference)
//
#include <hip/hip_runtime.h>

constexpr int B = 4, S = 2048, U = 1024, H = 16, DH = 64;
constexpr int MTOT = B * S;
constexpr int NT = S / 64;   // 32 key-tiles of 64

using bf16   = __bf16;
using f32x4  = __attribute__((ext_vector_type(4))) float;
using f32x16 = __attribute__((ext_vector_type(16))) float;
using bf16x8 = __attribute__((ext_vector_type(8))) bf16;
using bf16x4 = __attribute__((ext_vector_type(4))) bf16;
using u32x4  = __attribute__((ext_vector_type(4))) unsigned int;

__device__ __forceinline__ void gload16(const bf16* g, bf16* l) {
  __builtin_amdgcn_global_load_lds(
      (const __attribute__((address_space(1))) unsigned int*)g,
      (__attribute__((address_space(3))) unsigned int*)l, 16, 0, 0);
}

__device__ __forceinline__ float fexp2(float x) {
#if __has_builtin(__builtin_amdgcn_exp2f)
  return __builtin_amdgcn_exp2f(x);
#else
  return __expf(x * 0.6931471805599453f);
#endif
}

__device__ __forceinline__ f32x16 mfma32(bf16x8 a, bf16x8 b, f32x16 c) {
  return __builtin_amdgcn_mfma_f32_32x32x16_bf16(a, b, c, 0, 0, 0);
}

__device__ __forceinline__ unsigned packbf(float a, float b) {
  union { bf16 h; unsigned short s; } ua, ub;
  ua.h = (bf16)a; ub.h = (bf16)b;
  return ((unsigned)ub.s << 16) | (unsigned)ua.s;
}

// packed K layout: Kp[bh][t][tt][ks][ln][8] = K[s = t*64+tt*32+(ln&31)][h*64 + ks*16+(ln>>5)*8+j]
__device__ __forceinline__ size_t kpack_off(int M_, int col) {
  const int b = M_ >> 11, s = M_ & 2047;
  const int h = col >> 6, d = col & 63;
  const int bh = b * 16 + h;
  const int t = s >> 6, r64 = s & 63;
  const int tt = r64 >> 5, l31 = r64 & 31;
  const int ks = d >> 4, hi = (d >> 3) & 1, j = d & 7;
  const int ln = l31 + (hi << 5);
  return ((size_t)(bh * 32 + t) << 12) + (tt << 11) + (ks << 9) + (ln << 3) + j;
}

// packed V layout: Vp[bh][t][dt][ks][ln][8] = V[s = t*64+ks*16+(ln>>5)*8+j][h*64 + dt*32+(ln&31)]
__device__ __forceinline__ size_t vpack_off(int M_, int col) {
  const int b = M_ >> 11, s = M_ & 2047;
  const int h = col >> 6, d = col & 63;
  const int bh = b * 16 + h;
  const int j = s & 7, hi = (s >> 3) & 1, ks = (s >> 4) & 3, t = s >> 6;
  const int dt = d >> 5, l31 = d & 31;
  const int ln = l31 + (hi << 5);
  return ((size_t)(bh * 32 + t) << 12) + (dt << 11) + (ks << 9) + (ln << 3) + j;
}

// ---------- prep: fused {fp32->bf16 convert of q,k,v} + {4x weight transpose+convert} ----------
__global__ __launch_bounds__(256) void prep_kernel(
    const float* __restrict__ xq, const float* __restrict__ xk, const float* __restrict__ xv,
    bf16* __restrict__ oq, bf16* __restrict__ ok, bf16* __restrict__ ov,
    const float* __restrict__ w0, const float* __restrict__ w1,
    const float* __restrict__ w2, const float* __restrict__ w3,
    bf16* __restrict__ t0, bf16* __restrict__ t1,
    bf16* __restrict__ t2, bf16* __restrict__ t3) {
  __shared__ float tile[32][33];
  const int bid = blockIdx.x;
  const int t = threadIdx.x;
  if (bid < 12288) {
    const int z = bid >> 12, idx = bid & 4095;
    const float* x = z == 0 ? xq : z == 1 ? xk : xv;
    bf16* o       = z == 0 ? oq : z == 1 ? ok : ov;
    const size_t i = ((size_t)idx * 256 + t) * 8;
    const float4 v0 = *reinterpret_cast<const float4*>(x + i);
    const float4 v1 = *reinterpret_cast<const float4*>(x + i + 4);
    bf16x8 r;
    r[0] = (bf16)v0.x; r[1] = (bf16)v0.y; r[2] = (bf16)v0.z; r[3] = (bf16)v0.w;
    r[4] = (bf16)v1.x; r[5] = (bf16)v1.y; r[6] = (bf16)v1.z; r[7] = (bf16)v1.w;
    *reinterpret_cast<bf16x8*>(o + i) = r;
  } else {
    const int wb = bid - 12288;
    const int z = wb >> 10, ti = wb & 1023;
    const float* W = z == 0 ? w0 : z == 1 ? w1 : z == 2 ? w2 : w3;
    bf16* Wt       = z == 0 ? t0 : z == 1 ? t1 : z == 2 ? t2 : t3;
    const int k0 = (ti & 31) * 32, n0 = (ti >> 5) * 32;
    const int tx = t & 31, ty = t >> 5;
    for (int i = ty; i < 32; i += 8) tile[i][tx] = W[(size_t)(k0 + i) * U + n0 + tx];
    __syncthreads();
    for (int i = ty; i < 32; i += 8) Wt[(size_t)(n0 + i) * U + k0 + tx] = (bf16)tile[tx][i];
  }
}

// ---------- fused 4-GEMM: out = relu(A @ Wt^T + b) ----------
// 256x256 template, 8 waves (2M x 4N), BK=64, 128KB LDS 2-buffer. Staging is
// issue-early: ALL of K-tile t+1 staged in phases 0-1; phases 2-3 MFMA-only.
// One vmcnt(0)+barrier per K-tile. r12-verified slot swizzle.
__global__ __launch_bounds__(512, 2) void gemm4_kernel(
    const bf16* __restrict__ Qc, const bf16* __restrict__ Kc, const bf16* __restrict__ Vc,
    const bf16* __restrict__ wqt, const bf16* __restrict__ wkt,
    const bf16* __restrict__ wvt, const bf16* __restrict__ wrt,
    const float* __restrict__ bq, const float* __restrict__ bk,
    const float* __restrict__ bv, const float* __restrict__ br,
    bf16* __restrict__ oq, bf16* __restrict__ okp,
    bf16* __restrict__ ovp, bf16* __restrict__ orr) {
  const int bid = blockIdx.x;
  const int wg = (bid & 7) * 64 + (bid >> 3);   // bijective: 512 % 8 == 0
  const int z = wg >> 7, rem = wg & 127;
  const int bm = (rem >> 2) * 256, bn = (rem & 3) * 256;

  const bf16* A     = z == 0 ? Qc : z == 1 ? Kc : Vc;   // z==2,3 read Vcvt
  const bf16* Wt    = z == 0 ? wqt : z == 1 ? wkt : z == 2 ? wvt : wrt;
  const float* bias = z == 0 ? bq : z == 1 ? bk : z == 2 ? bv : br;

  const int tid = threadIdx.x, lane = tid & 63, w = tid >> 6;
  const int wr = w >> 2, wcn = w & 3;
  const int lm = lane & 15, hi = lane >> 4;

  __shared__ __align__(16) bf16 smem[65536];   // 128KB: [buf][A 16384 | B 16384]

  f32x4 acc[8][4];
#pragma unroll
  for (int i = 0; i < 8; ++i)
#pragma unroll
    for (int j = 0; j < 4; ++j) acc[i][j] = f32x4{0.f, 0.f, 0.f, 0.f};

  const int srow = tid >> 3, sslot = tid & 7;
  const int scol = (sslot ^ (srow & 7)) * 8;
  const bf16* gA = A  + (size_t)(bm + srow) * U + scol;
  const bf16* gB = Wt + (size_t)(bn + srow) * U + scol;

  auto stageA = [&](int buf, int half, int k0) {
    bf16* l = smem + buf * 32768 + (half * 128 + srow) * 64 + sslot * 8;
    gload16(gA + (size_t)(half * 128) * U + k0, l);
    gload16(gA + (size_t)(half * 128 + 64) * U + k0, l + 64 * 64);
  };
  auto stageB = [&](int buf, int half, int k0) {
    bf16* l = smem + buf * 32768 + 16384 + (half * 128 + srow) * 64 + sslot * 8;
    gload16(gB + (size_t)(half * 128) * U + k0, l);
    gload16(gB + (size_t)(half * 128 + 64) * U + k0, l + 64 * 64);
  };

  auto loadA = [&](int buf, int mi, int ks) {
    const int row = wr * 128 + mi * 16 + lm;
    const int slot = (ks * 4 + hi) ^ (lm & 7);
    return *reinterpret_cast<const bf16x8*>(smem + buf * 32768 + row * 64 + slot * 8);
  };
  auto loadB = [&](int buf, int ni, int ks) {
    const int row = wcn * 64 + ni * 16 + lm;
    const int slot = (ks * 4 + hi) ^ (lm & 7);
    return *reinterpret_cast<const bf16x8*>(smem + buf * 32768 + 16384 + row * 64 + slot * 8);
  };

  stageA(0, 0, 0); stageA(0, 1, 0); stageB(0, 0, 0); stageB(0, 1, 0);
  asm volatile("s_waitcnt vmcnt(0)" ::: "memory");
  __builtin_amdgcn_s_barrier();
  __builtin_amdgcn_sched_barrier(0);

  for (int t = 0; t < 16; ++t) {
    const int buf = t & 1, nbf = buf ^ 1;
    const int k1 = (t + 1) * 64;
    const bool pre = (t + 1) < 16;

    bf16x8 bfr[4][2];

    if (pre) { stageA(nbf, 0, k1); stageA(nbf, 1, k1); }
#pragma unroll
    for (int ni = 0; ni < 4; ++ni) {
      bfr[ni][0] = loadB(buf, ni, 0);
      bfr[ni][1] = loadB(buf, ni, 1);
    }
    {
      bf16x8 a00 = loadA(buf, 0, 0), a01 = loadA(buf, 0, 1);
      bf16x8 a10 = loadA(buf, 1, 0), a11 = loadA(buf, 1, 1);
      __builtin_amdgcn_s_setprio(1);
#pragma unroll
      for (int ni = 0; ni < 4; ++ni) {
        acc[0][ni] = __builtin_amdgcn_mfma_f32_16x16x32_bf16(a00, bfr[ni][0], acc[0][ni], 0, 0, 0);
        acc[0][ni] = __builtin_amdgcn_mfma_f32_16x16x32_bf16(a01, bfr[ni][1], acc[0][ni], 0, 0, 0);
        acc[1][ni] = __builtin_amdgcn_mfma_f32_16x16x32_bf16(a10, bfr[ni][0], acc[1][ni], 0, 0, 0);
        acc[1][ni] = __builtin_amdgcn_mfma_f32_16x16x32_bf16(a11, bfr[ni][1], acc[1][ni], 0, 0, 0);
      }
      __builtin_amdgcn_s_setprio(0);
    }
    if (pre) { stageB(nbf, 0, k1); stageB(nbf, 1, k1); }
    {
      bf16x8 a00 = loadA(buf, 2, 0), a01 = loadA(buf, 2, 1);
      bf16x8 a10 = loadA(buf, 3, 0), a11 = loadA(buf, 3, 1);
      __builtin_amdgcn_s_setprio(1);
#pragma unroll
      for (int ni = 0; ni < 4; ++ni) {
        acc[2][ni] = __builtin_amdgcn_mfma_f32_16x16x32_bf16(a00, bfr[ni][0], acc[2][ni], 0, 0, 0);
        acc[2][ni] = __builtin_amdgcn_mfma_f32_16x16x32_bf16(a01, bfr[ni][1], acc[2][ni], 0, 0, 0);
        acc[3][ni] = __builtin_amdgcn_mfma_f32_16x16x32_bf16(a10, bfr[ni][0], acc[3][ni], 0, 0, 0);
        acc[3][ni] = __builtin_amdgcn_mfma_f32_16x16x32_bf16(a11, bfr[ni][1], acc[3][ni], 0, 0, 0);
      }
      __builtin_amdgcn_s_setprio(0);
    }
    {
      bf16x8 a00 = loadA(buf, 4, 0), a01 = loadA(buf, 4, 1);
      bf16x8 a10 = loadA(buf, 5, 0), a11 = loadA(buf, 5, 1);
      __builtin_amdgcn_s_setprio(1);
#pragma unroll
      for (int ni = 0; ni < 4; ++ni) {
        acc[4][ni] = __builtin_amdgcn_mfma_f32_16x16x32_bf16(a00, bfr[ni][0], acc[4][ni], 0, 0, 0);
        acc[4][ni] = __builtin_amdgcn_mfma_f32_16x16x32_bf16(a01, bfr[ni][1], acc[4][ni], 0, 0, 0);
        acc[5][ni] = __builtin_amdgcn_mfma_f32_16x16x32_bf16(a10, bfr[ni][0], acc[5][ni], 0, 0, 0);
        acc[5][ni] = __builtin_amdgcn_mfma_f32_16x16x32_bf16(a11, bfr[ni][1], acc[5][ni], 0, 0, 0);
      }
      __builtin_amdgcn_s_setprio(0);
    }
    {
      bf16x8 a00 = loadA(buf, 6, 0), a01 = loadA(buf, 6, 1);
      bf16x8 a10 = loadA(buf, 7, 0), a11 = loadA(buf, 7, 1);
      __builtin_amdgcn_s_setprio(1);
#pragma unroll
      for (int ni = 0; ni < 4; ++ni) {
        acc[6][ni] = __builtin_amdgcn_mfma_f32_16x16x32_bf16(a00, bfr[ni][0], acc[6][ni], 0, 0, 0);
        acc[6][ni] = __builtin_amdgcn_mfma_f32_16x16x32_bf16(a01, bfr[ni][1], acc[6][ni], 0, 0, 0);
        acc[7][ni] = __builtin_amdgcn_mfma_f32_16x16x32_bf16(a10, bfr[ni][0], acc[7][ni], 0, 0, 0);
        acc[7][ni] = __builtin_amdgcn_mfma_f32_16x16x32_bf16(a11, bfr[ni][1], acc[7][ni], 0, 0, 0);
      }
      __builtin_amdgcn_s_setprio(0);
    }

    if (pre) {
      asm volatile("s_waitcnt vmcnt(0)" ::: "memory");
      __builtin_amdgcn_s_barrier();
      __builtin_amdgcn_sched_barrier(0);
    }
  }

  const int mb = bm + wr * 128 + hi * 4;
  const int nb = bn + wcn * 64 + lm;
  if (z == 1) {
#pragma unroll
    for (int ni = 0; ni < 4; ++ni) {
      const float bv_ = bias[nb + ni * 16];
#pragma unroll
      for (int mi = 0; mi < 8; ++mi)
#pragma unroll
        for (int r = 0; r < 4; ++r) {
          const float vv = fmaxf(acc[mi][ni][r] + bv_, 0.f);
          okp[kpack_off(mb + mi * 16 + r, nb + ni * 16)] = (bf16)vv;
        }
    }
  } else if (z == 2) {
#pragma unroll
    for (int ni = 0; ni < 4; ++ni) {
      const float bv_ = bias[nb + ni * 16];
#pragma unroll
      for (int mi = 0; mi < 8; ++mi)
#pragma unroll
        for (int r = 0; r < 4; ++r) {
          const float vv = fmaxf(acc[mi][ni][r] + bv_, 0.f);
          ovp[vpack_off(mb + mi * 16 + r, nb + ni * 16)] = (bf16)vv;
        }
    }
  } else {
    bf16* out = z == 0 ? oq : orr;
#pragma unroll
    for (int ni = 0; ni < 4; ++ni) {
      const float bv_ = bias[nb + ni * 16];
#pragma unroll
      for (int mi = 0; mi < 8; ++mi)
#pragma unroll
        for (int r = 0; r < 4; ++r) {
          const float vv = fmaxf(acc[mi][ni][r] + bv_, 0.f);
          out[(size_t)(mb + mi * 16 + r) * U + nb + ni * 16] = (bf16)vv;
        }
    }
  }
}

// ---------- flash attention: packed K/V, 2-buffer x 128-key big-tiles ----------
// 64 q-rows per wave (2 q-groups share fragment reads); 16 barriers.
// Softmax denominator now accumulated on VALU during the exp2/pack stream
// (each lane's pre-pack values all belong to q = lane&31), replacing the 8
// osum ones-MFMAs per sub-tile (-20% matrix work, shorter chain tail).
// Partner-half merge + 1/sum redistribution deferred to a one-time epilogue.
__global__ __launch_bounds__(256, 2) void attn_kernel(
    const bf16* __restrict__ Q, const bf16* __restrict__ Kp,
    const bf16* __restrict__ Vp, bf16* __restrict__ att) {
  const int bid = blockIdx.x;
  const int swz = (bid & 7) * 64 + (bid >> 3);     // 512 blocks, 8 per XCD chunk
  const int bh = swz >> 3, qx = swz & 7;
  const int b = bh >> 4, h = bh & 15;
  const int tid = threadIdx.x;
  const int w = tid >> 6, lane = tid & 63;
  const int l31 = lane & 31, hi8 = lane >> 5;
  const int q0 = qx * 256 + w * 64;

  __shared__ __align__(16) bf16 kv[2][16384];   // per buf: 2 sub-tiles x {K 4096 | V 4096}

  const float qscale = 0.18033688011111606f;  // log2(e)/sqrt(DH)

  bf16x8 qf[2][4];
#pragma unroll
  for (int qg = 0; qg < 2; ++qg) {
    const bf16* qbase = Q + ((size_t)b * S + q0 + qg * 32 + l31) * U + h * DH + hi8 * 8;
#pragma unroll
    for (int ks = 0; ks < 4; ++ks) {
      bf16x8 v = *reinterpret_cast<const bf16x8*>(qbase + ks * 16);
#pragma unroll
      for (int j = 0; j < 8; ++j) v[j] = (bf16)((float)v[j] * qscale);
      qf[qg][ks] = v;
    }
  }

  f32x16 o[2][2];
  float psum[2] = {0.f, 0.f};   // own-half row-sum for q = l31 (per q-group)
#pragma unroll
  for (int qg = 0; qg < 2; ++qg) { o[qg][0] = (f32x16)0.f; o[qg][1] = (f32x16)0.f; }

  const bf16* kpb = Kp + (size_t)bh * 32 * 4096;
  const bf16* vpb = Vp + (size_t)bh * 32 * 4096;

  auto stagekv2 = [&](int buf, int bt) {
#pragma unroll
    for (int st = 0; st < 2; ++st) {
      const size_t toff = (size_t)(bt * 2 + st) * 4096;
      bf16* base = &kv[buf][st * 8192];
      gload16(kpb + toff + tid * 8,        base + tid * 8);
      gload16(kpb + toff + 2048 + tid * 8, base + 2048 + tid * 8);
      gload16(vpb + toff + tid * 8,        base + 4096 + tid * 8);
      gload16(vpb + toff + 2048 + tid * 8, base + 6144 + tid * 8);
    }
  };

  stagekv2(0, 0);
  asm volatile("s_waitcnt vmcnt(0)" ::: "memory");
  __builtin_amdgcn_s_barrier();
  __builtin_amdgcn_sched_barrier(0);

  for (int bt = 0; bt < 16; ++bt) {
    const int buf = bt & 1;
    if (bt + 1 < 16) stagekv2(buf ^ 1, bt + 1);

#pragma unroll
    for (int st = 0; st < 2; ++st) {
      const bf16* sub = &kv[buf][st * 8192];

      // S^T = K Q^T for both q-groups; kf loaded in tt-halves to cap VGPR
      f32x16 s[2][2];
      s[0][0] = (f32x16)0.f; s[0][1] = (f32x16)0.f;
      s[1][0] = (f32x16)0.f; s[1][1] = (f32x16)0.f;
#pragma unroll
      for (int tt = 0; tt < 2; ++tt) {
        bf16x8 kf4[4];
#pragma unroll
        for (int ks = 0; ks < 4; ++ks)
          kf4[ks] = *reinterpret_cast<const bf16x8*>(sub + (tt * 4 + ks) * 512 + lane * 8);
        __builtin_amdgcn_s_setprio(1);
#pragma unroll
        for (int ks = 0; ks < 4; ++ks) {
          s[0][tt] = mfma32(kf4[ks], qf[0][ks], s[0][tt]);
          s[1][tt] = mfma32(kf4[ks], qf[1][ks], s[1][tt]);
        }
        __builtin_amdgcn_s_setprio(0);
      }

      // P = exp2(s); accumulate own-half row-sum on VALU; pack; half-exchange
      u32x4 fw[2][4];
#pragma unroll
      for (int qg = 0; qg < 2; ++qg) {
        unsigned wpk[16];
        float psub = 0.f;
#pragma unroll
        for (int i = 0; i < 8; ++i) {
          const float pa = fexp2(s[qg][0][2 * i]);
          const float pb = fexp2(s[qg][0][2 * i + 1]);
          const float pc = fexp2(s[qg][1][2 * i]);
          const float pd = fexp2(s[qg][1][2 * i + 1]);
          psub += (pa + pb) + (pc + pd);
          wpk[i]     = packbf(pa, pb);
          wpk[8 + i] = packbf(pc, pd);
        }
        psum[qg] += psub;
#pragma unroll
        for (int fi = 0; fi < 4; ++fi) {
          unsigned a0 = wpk[fi * 4 + 0], b0 = wpk[fi * 4 + 2];
          unsigned a1 = wpk[fi * 4 + 1], b1 = wpk[fi * 4 + 3];
          asm("v_permlane32_swap_b32 %0, %1" : "+v"(a0), "+v"(b0));
          asm("v_permlane32_swap_b32 %0, %1" : "+v"(a1), "+v"(b1));
          fw[qg][fi] = u32x4{a0, a1, b0, b1};
        }
      }

      // O += P V (vf loaded in dt-halves)
#pragma unroll
      for (int dt = 0; dt < 2; ++dt) {
        bf16x8 vf4[4];
#pragma unroll
        for (int ks = 0; ks < 4; ++ks)
          vf4[ks] = *reinterpret_cast<const bf16x8*>(sub + 4096 + (dt * 4 + ks) * 512 + lane * 8);
        __builtin_amdgcn_s_setprio(1);
#pragma unroll
        for (int ks = 0; ks < 4; ++ks) {
          o[0][dt] = mfma32(__builtin_bit_cast(bf16x8, fw[0][ks]), vf4[ks], o[0][dt]);
          o[1][dt] = mfma32(__builtin_bit_cast(bf16x8, fw[1][ks]), vf4[ks], o[1][dt]);
        }
        __builtin_amdgcn_s_setprio(0);
      }
    }

    if (bt + 1 < 16) {
      asm volatile("s_waitcnt vmcnt(0)" ::: "memory");
      __builtin_amdgcn_s_barrier();
      __builtin_amdgcn_sched_barrier(0);
    }
  }

  // epilogue: merge partner halves of psum, redistribute 1/sum to C-layout rows
#pragma unroll
  for (int qg = 0; qg < 2; ++qg) {
    float t1 = psum[qg], t2 = psum[qg];
    asm("v_permlane32_swap_b32 %0, %1" : "+v"(t1), "+v"(t2));
    const float psinv = 1.f / (t1 + t2);   // valid at all lanes; lane l<32 holds q=l
    bf16* obase = att + ((size_t)b * S + q0 + qg * 32) * U + h * DH + l31;
#pragma unroll
    for (int r = 0; r < 16; ++r) {
      const int row = (r & 3) + 8 * (r >> 2) + 4 * hi8;
      const float lr = __shfl(psinv, row);
      obase[(size_t)row * U]      = (bf16)(o[qg][0][r] * lr);
      obase[(size_t)row * U + 32] = (bf16)(o[qg][1][r] * lr);
    }
  }
}

// ---------- epilogue: x = relu(att + vres); LayerNorm(x)*gamma + beta ----------
__global__ __launch_bounds__(256) void ln_kernel(
    const bf16* __restrict__ att, const bf16* __restrict__ vres,
    const float* __restrict__ gamma, const float* __restrict__ beta,
    float* __restrict__ out) {
  const int w = threadIdx.x >> 6, lane = threadIdx.x & 63;
  const int row = blockIdx.x * 4 + w;
  const int c0 = lane * 16;
  const bf16* ar = att  + (size_t)row * U + c0;
  const bf16* vr = vres + (size_t)row * U + c0;

  const bf16x8 a0 = *reinterpret_cast<const bf16x8*>(ar);
  const bf16x8 a1 = *reinterpret_cast<const bf16x8*>(ar + 8);
  const bf16x8 v0 = *reinterpret_cast<const bf16x8*>(vr);
  const bf16x8 v1 = *reinterpret_cast<const bf16x8*>(vr + 8);

  float x[16];
  float sum = 0.f, sq = 0.f;
#pragma unroll
  for (int i = 0; i < 8; ++i) {
    x[i]     = fmaxf((float)a0[i] + (float)v0[i], 0.f);
    x[8 + i] = fmaxf((float)a1[i] + (float)v1[i], 0.f);
  }
#pragma unroll
  for (int i = 0; i < 16; ++i) { sum += x[i]; sq += x[i] * x[i]; }
#pragma unroll
  for (int mm = 1; mm < 64; mm <<= 1) {
    sum += __shfl_xor(sum, mm);
    sq  += __shfl_xor(sq, mm);
  }
  const float mean = sum * (1.f / U);
  float var = sq * (1.f / U) - mean * mean;
  var = fmaxf(var, 0.f);
  const float inv = rsqrtf(var + 1e-8f);

  float* orow = out + (size_t)row * U + c0;
#pragma unroll
  for (int j = 0; j < 4; ++j) {
    const float4 g = *reinterpret_cast<const float4*>(gamma + c0 + j * 4);
    const float4 bt = *reinterpret_cast<const float4*>(beta + c0 + j * 4);
    float4 o;
    o.x = g.x * ((x[j * 4 + 0] - mean) * inv) + bt.x;
    o.y = g.y * ((x[j * 4 + 1] - mean) * inv) + bt.y;
    o.z = g.z * ((x[j * 4 + 2] - mean) * inv) + bt.z;
    o.w = g.w * ((x[j * 4 + 3] - mean) * inv) + bt.w;
    *reinterpret_cast<float4*>(orow + j * 4) = o;
  }
}

extern "C" void kernel_launch(void* const* d_in, const int* in_sizes, int n_in,
                              void* d_out, int out_size, void* d_ws, size_t ws_size,
                              hipStream_t stream) {
  const float* queries = (const float*)d_in[0];
  const float* keys    = (const float*)d_in[1];
  const float* values  = (const float*)d_in[2];
  const float* Wq = (const float*)d_in[3];
  const float* bq = (const float*)d_in[4];
  const float* Wk = (const float*)d_in[5];
  const float* bk = (const float*)d_in[6];
  const float* Wv = (const float*)d_in[7];
  const float* bv = (const float*)d_in[8];
  const float* Wr = (const float*)d_in[9];
  const float* br = (const float*)d_in[10];
  const float* gamma = (const float*)d_in[11];
  const float* beta  = (const float*)d_in[12];
  float* out = (float*)d_out;

  char* ws = (char*)d_ws;
  const size_t MB = 1024 * 1024;
  bf16* wqt  = (bf16*)(ws + 0 * MB);
  bf16* wkt  = (bf16*)(ws + 2 * MB);
  bf16* wvt  = (bf16*)(ws + 4 * MB);
  bf16* wrt  = (bf16*)(ws + 6 * MB);
  bf16* Qcvt = (bf16*)(ws + 8 * MB);    // dead after gemm -> attb aliases
  bf16* Kcvt = (bf16*)(ws + 24 * MB);   // dead after gemm -> Rb aliases (Rb written by gemm z=3)
  bf16* Vcvt = (bf16*)(ws + 40 * MB);
  bf16* Qb   = (bf16*)(ws + 56 * MB);
  bf16* Kp   = (bf16*)(ws + 72 * MB);
  bf16* Vp   = (bf16*)(ws + 88 * MB);   // total 104 MB
  bf16* attb = Qcvt;
  bf16* Rb   = Kcvt;

  prep_kernel<<<dim3(16384), 256, 0, stream>>>(
      queries, keys, values, Qcvt, Kcvt, Vcvt,
      Wq, Wk, Wv, Wr, wqt, wkt, wvt, wrt);
  gemm4_kernel<<<dim3(512), 512, 0, stream>>>(
      Qcvt, Kcvt, Vcvt, wqt, wkt, wvt, wrt, bq, bk, bv, br, Qb, Kp, Vp, Rb);
  attn_kernel<<<dim3(512), 256, 0, stream>>>(Qb, Kp, Vp, attb);
  ln_kernel<<<dim3(MTOT / 4), 256, 0, stream>>>(attb, Rb, gamma, beta, out);
}

// Round 21
// 194.896 us; speedup vs baseline: 1.0651x; 1.0651x over previous
//
#include <hip/hip_runtime.h>

constexpr int B = 4, S = 2048, U = 1024, H = 16, DH = 64;
constexpr int MTOT = B * S;
constexpr int NT = S / 64;   // 32 key-tiles of 64

using bf16   = __bf16;
using f32x4  = __attribute__((ext_vector_type(4))) float;
using f32x16 = __attribute__((ext_vector_type(16))) float;
using bf16x8 = __attribute__((ext_vector_type(8))) bf16;
using bf16x4 = __attribute__((ext_vector_type(4))) bf16;
using u32x4  = __attribute__((ext_vector_type(4))) unsigned int;

__device__ __forceinline__ void gload16(const bf16* g, bf16* l) {
  __builtin_amdgcn_global_load_lds(
      (const __attribute__((address_space(1))) unsigned int*)g,
      (__attribute__((address_space(3))) unsigned int*)l, 16, 0, 0);
}

__device__ __forceinline__ float fexp2(float x) {
#if __has_builtin(__builtin_amdgcn_exp2f)
  return __builtin_amdgcn_exp2f(x);
#else
  return __expf(x * 0.6931471805599453f);
#endif
}

__device__ __forceinline__ f32x16 mfma32(bf16x8 a, bf16x8 b, f32x16 c) {
  return __builtin_amdgcn_mfma_f32_32x32x16_bf16(a, b, c, 0, 0, 0);
}

__device__ __forceinline__ unsigned packbf(float a, float b) {
  union { bf16 h; unsigned short s; } ua, ub;
  ua.h = (bf16)a; ub.h = (bf16)b;
  return ((unsigned)ub.s << 16) | (unsigned)ua.s;
}

// packed K layout: Kp[bh][t][tt][ks][ln][8] = K[s = t*64+tt*32+(ln&31)][h*64 + ks*16+(ln>>5)*8+j]
__device__ __forceinline__ size_t kpack_off(int M_, int col) {
  const int b = M_ >> 11, s = M_ & 2047;
  const int h = col >> 6, d = col & 63;
  const int bh = b * 16 + h;
  const int t = s >> 6, r64 = s & 63;
  const int tt = r64 >> 5, l31 = r64 & 31;
  const int ks = d >> 4, hi = (d >> 3) & 1, j = d & 7;
  const int ln = l31 + (hi << 5);
  return ((size_t)(bh * 32 + t) << 12) + (tt << 11) + (ks << 9) + (ln << 3) + j;
}

// packed V layout: Vp[bh][t][dt][ks][ln][8] = V[s = t*64+ks*16+(ln>>5)*8+j][h*64 + dt*32+(ln&31)]
__device__ __forceinline__ size_t vpack_off(int M_, int col) {
  const int b = M_ >> 11, s = M_ & 2047;
  const int h = col >> 6, d = col & 63;
  const int bh = b * 16 + h;
  const int j = s & 7, hi = (s >> 3) & 1, ks = (s >> 4) & 3, t = s >> 6;
  const int dt = d >> 5, l31 = d & 31;
  const int ln = l31 + (hi << 5);
  return ((size_t)(bh * 32 + t) << 12) + (dt << 11) + (ks << 9) + (ln << 3) + j;
}

// ---------- prep: fused {fp32->bf16 convert of q,k,v} + {4x weight transpose+convert} ----------
__global__ __launch_bounds__(256) void prep_kernel(
    const float* __restrict__ xq, const float* __restrict__ xk, const float* __restrict__ xv,
    bf16* __restrict__ oq, bf16* __restrict__ ok, bf16* __restrict__ ov,
    const float* __restrict__ w0, const float* __restrict__ w1,
    const float* __restrict__ w2, const float* __restrict__ w3,
    bf16* __restrict__ t0, bf16* __restrict__ t1,
    bf16* __restrict__ t2, bf16* __restrict__ t3) {
  __shared__ float tile[32][33];
  const int bid = blockIdx.x;
  const int t = threadIdx.x;
  if (bid < 12288) {
    const int z = bid >> 12, idx = bid & 4095;
    const float* x = z == 0 ? xq : z == 1 ? xk : xv;
    bf16* o       = z == 0 ? oq : z == 1 ? ok : ov;
    const size_t i = ((size_t)idx * 256 + t) * 8;
    const float4 v0 = *reinterpret_cast<const float4*>(x + i);
    const float4 v1 = *reinterpret_cast<const float4*>(x + i + 4);
    bf16x8 r;
    r[0] = (bf16)v0.x; r[1] = (bf16)v0.y; r[2] = (bf16)v0.z; r[3] = (bf16)v0.w;
    r[4] = (bf16)v1.x; r[5] = (bf16)v1.y; r[6] = (bf16)v1.z; r[7] = (bf16)v1.w;
    *reinterpret_cast<bf16x8*>(o + i) = r;
  } else {
    const int wb = bid - 12288;
    const int z = wb >> 10, ti = wb & 1023;
    const float* W = z == 0 ? w0 : z == 1 ? w1 : z == 2 ? w2 : w3;
    bf16* Wt       = z == 0 ? t0 : z == 1 ? t1 : z == 2 ? t2 : t3;
    const int k0 = (ti & 31) * 32, n0 = (ti >> 5) * 32;
    const int tx = t & 31, ty = t >> 5;
    for (int i = ty; i < 32; i += 8) tile[i][tx] = W[(size_t)(k0 + i) * U + n0 + tx];
    __syncthreads();
    for (int i = ty; i < 32; i += 8) Wt[(size_t)(n0 + i) * U + k0 + tx] = (bf16)tile[tx][i];
  }
}

// ---------- fused 4-GEMM: out = relu(A @ Wt^T + b) ----------
// 256x256 template, 8 waves (2M x 4N), BK=64, 128KB LDS 2-buffer. Staging is
// issue-early: ALL of K-tile t+1 staged in phases 0-1; phases 2-3 MFMA-only.
// One vmcnt(0)+barrier per K-tile. r12-verified slot swizzle.
__global__ __launch_bounds__(512, 2) void gemm4_kernel(
    const bf16* __restrict__ Qc, const bf16* __restrict__ Kc, const bf16* __restrict__ Vc,
    const bf16* __restrict__ wqt, const bf16* __restrict__ wkt,
    const bf16* __restrict__ wvt, const bf16* __restrict__ wrt,
    const float* __restrict__ bq, const float* __restrict__ bk,
    const float* __restrict__ bv, const float* __restrict__ br,
    bf16* __restrict__ oq, bf16* __restrict__ okp,
    bf16* __restrict__ ovp, bf16* __restrict__ orr) {
  const int bid = blockIdx.x;
  const int wg = (bid & 7) * 64 + (bid >> 3);   // bijective: 512 % 8 == 0
  const int z = wg >> 7, rem = wg & 127;
  const int bm = (rem >> 2) * 256, bn = (rem & 3) * 256;

  const bf16* A     = z == 0 ? Qc : z == 1 ? Kc : Vc;   // z==2,3 read Vcvt
  const bf16* Wt    = z == 0 ? wqt : z == 1 ? wkt : z == 2 ? wvt : wrt;
  const float* bias = z == 0 ? bq : z == 1 ? bk : z == 2 ? bv : br;

  const int tid = threadIdx.x, lane = tid & 63, w = tid >> 6;
  const int wr = w >> 2, wcn = w & 3;
  const int lm = lane & 15, hi = lane >> 4;

  __shared__ __align__(16) bf16 smem[65536];   // 128KB: [buf][A 16384 | B 16384]

  f32x4 acc[8][4];
#pragma unroll
  for (int i = 0; i < 8; ++i)
#pragma unroll
    for (int j = 0; j < 4; ++j) acc[i][j] = f32x4{0.f, 0.f, 0.f, 0.f};

  const int srow = tid >> 3, sslot = tid & 7;
  const int scol = (sslot ^ (srow & 7)) * 8;
  const bf16* gA = A  + (size_t)(bm + srow) * U + scol;
  const bf16* gB = Wt + (size_t)(bn + srow) * U + scol;

  auto stageA = [&](int buf, int half, int k0) {
    bf16* l = smem + buf * 32768 + (half * 128 + srow) * 64 + sslot * 8;
    gload16(gA + (size_t)(half * 128) * U + k0, l);
    gload16(gA + (size_t)(half * 128 + 64) * U + k0, l + 64 * 64);
  };
  auto stageB = [&](int buf, int half, int k0) {
    bf16* l = smem + buf * 32768 + 16384 + (half * 128 + srow) * 64 + sslot * 8;
    gload16(gB + (size_t)(half * 128) * U + k0, l);
    gload16(gB + (size_t)(half * 128 + 64) * U + k0, l + 64 * 64);
  };

  auto loadA = [&](int buf, int mi, int ks) {
    const int row = wr * 128 + mi * 16 + lm;
    const int slot = (ks * 4 + hi) ^ (lm & 7);
    return *reinterpret_cast<const bf16x8*>(smem + buf * 32768 + row * 64 + slot * 8);
  };
  auto loadB = [&](int buf, int ni, int ks) {
    const int row = wcn * 64 + ni * 16 + lm;
    const int slot = (ks * 4 + hi) ^ (lm & 7);
    return *reinterpret_cast<const bf16x8*>(smem + buf * 32768 + 16384 + row * 64 + slot * 8);
  };

  stageA(0, 0, 0); stageA(0, 1, 0); stageB(0, 0, 0); stageB(0, 1, 0);
  asm volatile("s_waitcnt vmcnt(0)" ::: "memory");
  __builtin_amdgcn_s_barrier();
  __builtin_amdgcn_sched_barrier(0);

  for (int t = 0; t < 16; ++t) {
    const int buf = t & 1, nbf = buf ^ 1;
    const int k1 = (t + 1) * 64;
    const bool pre = (t + 1) < 16;

    bf16x8 bfr[4][2];

    if (pre) { stageA(nbf, 0, k1); stageA(nbf, 1, k1); }
#pragma unroll
    for (int ni = 0; ni < 4; ++ni) {
      bfr[ni][0] = loadB(buf, ni, 0);
      bfr[ni][1] = loadB(buf, ni, 1);
    }
    {
      bf16x8 a00 = loadA(buf, 0, 0), a01 = loadA(buf, 0, 1);
      bf16x8 a10 = loadA(buf, 1, 0), a11 = loadA(buf, 1, 1);
      __builtin_amdgcn_s_setprio(1);
#pragma unroll
      for (int ni = 0; ni < 4; ++ni) {
        acc[0][ni] = __builtin_amdgcn_mfma_f32_16x16x32_bf16(a00, bfr[ni][0], acc[0][ni], 0, 0, 0);
        acc[0][ni] = __builtin_amdgcn_mfma_f32_16x16x32_bf16(a01, bfr[ni][1], acc[0][ni], 0, 0, 0);
        acc[1][ni] = __builtin_amdgcn_mfma_f32_16x16x32_bf16(a10, bfr[ni][0], acc[1][ni], 0, 0, 0);
        acc[1][ni] = __builtin_amdgcn_mfma_f32_16x16x32_bf16(a11, bfr[ni][1], acc[1][ni], 0, 0, 0);
      }
      __builtin_amdgcn_s_setprio(0);
    }
    if (pre) { stageB(nbf, 0, k1); stageB(nbf, 1, k1); }
    {
      bf16x8 a00 = loadA(buf, 2, 0), a01 = loadA(buf, 2, 1);
      bf16x8 a10 = loadA(buf, 3, 0), a11 = loadA(buf, 3, 1);
      __builtin_amdgcn_s_setprio(1);
#pragma unroll
      for (int ni = 0; ni < 4; ++ni) {
        acc[2][ni] = __builtin_amdgcn_mfma_f32_16x16x32_bf16(a00, bfr[ni][0], acc[2][ni], 0, 0, 0);
        acc[2][ni] = __builtin_amdgcn_mfma_f32_16x16x32_bf16(a01, bfr[ni][1], acc[2][ni], 0, 0, 0);
        acc[3][ni] = __builtin_amdgcn_mfma_f32_16x16x32_bf16(a10, bfr[ni][0], acc[3][ni], 0, 0, 0);
        acc[3][ni] = __builtin_amdgcn_mfma_f32_16x16x32_bf16(a11, bfr[ni][1], acc[3][ni], 0, 0, 0);
      }
      __builtin_amdgcn_s_setprio(0);
    }
    {
      bf16x8 a00 = loadA(buf, 4, 0), a01 = loadA(buf, 4, 1);
      bf16x8 a10 = loadA(buf, 5, 0), a11 = loadA(buf, 5, 1);
      __builtin_amdgcn_s_setprio(1);
#pragma unroll
      for (int ni = 0; ni < 4; ++ni) {
        acc[4][ni] = __builtin_amdgcn_mfma_f32_16x16x32_bf16(a00, bfr[ni][0], acc[4][ni], 0, 0, 0);
        acc[4][ni] = __builtin_amdgcn_mfma_f32_16x16x32_bf16(a01, bfr[ni][1], acc[4][ni], 0, 0, 0);
        acc[5][ni] = __builtin_amdgcn_mfma_f32_16x16x32_bf16(a10, bfr[ni][0], acc[5][ni], 0, 0, 0);
        acc[5][ni] = __builtin_amdgcn_mfma_f32_16x16x32_bf16(a11, bfr[ni][1], acc[5][ni], 0, 0, 0);
      }
      __builtin_amdgcn_s_setprio(0);
    }
    {
      bf16x8 a00 = loadA(buf, 6, 0), a01 = loadA(buf, 6, 1);
      bf16x8 a10 = loadA(buf, 7, 0), a11 = loadA(buf, 7, 1);
      __builtin_amdgcn_s_setprio(1);
#pragma unroll
      for (int ni = 0; ni < 4; ++ni) {
        acc[6][ni] = __builtin_amdgcn_mfma_f32_16x16x32_bf16(a00, bfr[ni][0], acc[6][ni], 0, 0, 0);
        acc[6][ni] = __builtin_amdgcn_mfma_f32_16x16x32_bf16(a01, bfr[ni][1], acc[6][ni], 0, 0, 0);
        acc[7][ni] = __builtin_amdgcn_mfma_f32_16x16x32_bf16(a10, bfr[ni][0], acc[7][ni], 0, 0, 0);
        acc[7][ni] = __builtin_amdgcn_mfma_f32_16x16x32_bf16(a11, bfr[ni][1], acc[7][ni], 0, 0, 0);
      }
      __builtin_amdgcn_s_setprio(0);
    }

    if (pre) {
      asm volatile("s_waitcnt vmcnt(0)" ::: "memory");
      __builtin_amdgcn_s_barrier();
      __builtin_amdgcn_sched_barrier(0);
    }
  }

  const int mb = bm + wr * 128 + hi * 4;
  const int nb = bn + wcn * 64 + lm;
  if (z == 1) {
#pragma unroll
    for (int ni = 0; ni < 4; ++ni) {
      const float bv_ = bias[nb + ni * 16];
#pragma unroll
      for (int mi = 0; mi < 8; ++mi)
#pragma unroll
        for (int r = 0; r < 4; ++r) {
          const float vv = fmaxf(acc[mi][ni][r] + bv_, 0.f);
          okp[kpack_off(mb + mi * 16 + r, nb + ni * 16)] = (bf16)vv;
        }
    }
  } else if (z == 2) {
#pragma unroll
    for (int ni = 0; ni < 4; ++ni) {
      const float bv_ = bias[nb + ni * 16];
#pragma unroll
      for (int mi = 0; mi < 8; ++mi)
#pragma unroll
        for (int r = 0; r < 4; ++r) {
          const float vv = fmaxf(acc[mi][ni][r] + bv_, 0.f);
          ovp[vpack_off(mb + mi * 16 + r, nb + ni * 16)] = (bf16)vv;
        }
    }
  } else {
    bf16* out = z == 0 ? oq : orr;
#pragma unroll
    for (int ni = 0; ni < 4; ++ni) {
      const float bv_ = bias[nb + ni * 16];
#pragma unroll
      for (int mi = 0; mi < 8; ++mi)
#pragma unroll
        for (int r = 0; r < 4; ++r) {
          const float vv = fmaxf(acc[mi][ni][r] + bv_, 0.f);
          out[(size_t)(mb + mi * 16 + r) * U + nb + ni * 16] = (bf16)vv;
        }
    }
  }
}

// ---------- flash attention: packed K/V, 2-buffer x 128-key big-tiles ----------
// 64 q-rows per wave (2 q-groups share fragment reads). TWO 64-key sub-tiles per
// barrier period. Swapped QK^T (32x32x16); no-max softmax; osum via ones-MFMA
// (rides free in the matrix pipe -- r20 proved VALU is the binding pipe);
// permlane half-exchange.
__global__ __launch_bounds__(256, 2) void attn_kernel(
    const bf16* __restrict__ Q, const bf16* __restrict__ Kp,
    const bf16* __restrict__ Vp, bf16* __restrict__ att) {
  const int bid = blockIdx.x;
  const int swz = (bid & 7) * 64 + (bid >> 3);     // 512 blocks, 8 per XCD chunk
  const int bh = swz >> 3, qx = swz & 7;
  const int b = bh >> 4, h = bh & 15;
  const int tid = threadIdx.x;
  const int w = tid >> 6, lane = tid & 63;
  const int l31 = lane & 31, hi8 = lane >> 5;
  const int q0 = qx * 256 + w * 64;

  __shared__ __align__(16) bf16 kv[2][16384];   // per buf: 2 sub-tiles x {K 4096 | V 4096}

  const float qscale = 0.18033688011111606f;  // log2(e)/sqrt(DH)

  bf16x8 qf[2][4];
#pragma unroll
  for (int qg = 0; qg < 2; ++qg) {
    const bf16* qbase = Q + ((size_t)b * S + q0 + qg * 32 + l31) * U + h * DH + hi8 * 8;
#pragma unroll
    for (int ks = 0; ks < 4; ++ks) {
      bf16x8 v = *reinterpret_cast<const bf16x8*>(qbase + ks * 16);
#pragma unroll
      for (int j = 0; j < 8; ++j) v[j] = (bf16)((float)v[j] * qscale);
      qf[qg][ks] = v;
    }
  }

  bf16x8 onesf;
#pragma unroll
  for (int j = 0; j < 8; ++j) onesf[j] = (bf16)1.f;

  f32x16 o[2][2], osum[2];
#pragma unroll
  for (int qg = 0; qg < 2; ++qg) {
    o[qg][0] = (f32x16)0.f; o[qg][1] = (f32x16)0.f; osum[qg] = (f32x16)0.f;
  }

  const bf16* kpb = Kp + (size_t)bh * 32 * 4096;
  const bf16* vpb = Vp + (size_t)bh * 32 * 4096;

  auto stagekv2 = [&](int buf, int bt) {
#pragma unroll
    for (int st = 0; st < 2; ++st) {
      const size_t toff = (size_t)(bt * 2 + st) * 4096;
      bf16* base = &kv[buf][st * 8192];
      gload16(kpb + toff + tid * 8,        base + tid * 8);
      gload16(kpb + toff + 2048 + tid * 8, base + 2048 + tid * 8);
      gload16(vpb + toff + tid * 8,        base + 4096 + tid * 8);
      gload16(vpb + toff + 2048 + tid * 8, base + 6144 + tid * 8);
    }
  };

  stagekv2(0, 0);
  asm volatile("s_waitcnt vmcnt(0)" ::: "memory");
  __builtin_amdgcn_s_barrier();
  __builtin_amdgcn_sched_barrier(0);

  for (int bt = 0; bt < 16; ++bt) {
    const int buf = bt & 1;
    if (bt + 1 < 16) stagekv2(buf ^ 1, bt + 1);

#pragma unroll
    for (int st = 0; st < 2; ++st) {
      const bf16* sub = &kv[buf][st * 8192];

      // S^T = K Q^T for both q-groups; kf loaded in tt-halves to cap VGPR
      f32x16 s[2][2];
      s[0][0] = (f32x16)0.f; s[0][1] = (f32x16)0.f;
      s[1][0] = (f32x16)0.f; s[1][1] = (f32x16)0.f;
#pragma unroll
      for (int tt = 0; tt < 2; ++tt) {
        bf16x8 kf4[4];
#pragma unroll
        for (int ks = 0; ks < 4; ++ks)
          kf4[ks] = *reinterpret_cast<const bf16x8*>(sub + (tt * 4 + ks) * 512 + lane * 8);
        __builtin_amdgcn_s_setprio(1);
#pragma unroll
        for (int ks = 0; ks < 4; ++ks) {
          s[0][tt] = mfma32(kf4[ks], qf[0][ks], s[0][tt]);
          s[1][tt] = mfma32(kf4[ks], qf[1][ks], s[1][tt]);
        }
        __builtin_amdgcn_s_setprio(0);
      }

      // P = exp2(s); pack; half-exchange
      u32x4 fw[2][4];
#pragma unroll
      for (int qg = 0; qg < 2; ++qg) {
        unsigned wpk[16];
#pragma unroll
        for (int i = 0; i < 8; ++i) {
          wpk[i]     = packbf(fexp2(s[qg][0][2 * i]), fexp2(s[qg][0][2 * i + 1]));
          wpk[8 + i] = packbf(fexp2(s[qg][1][2 * i]), fexp2(s[qg][1][2 * i + 1]));
        }
#pragma unroll
        for (int fi = 0; fi < 4; ++fi) {
          unsigned a0 = wpk[fi * 4 + 0], b0 = wpk[fi * 4 + 2];
          unsigned a1 = wpk[fi * 4 + 1], b1 = wpk[fi * 4 + 3];
          asm("v_permlane32_swap_b32 %0, %1" : "+v"(a0), "+v"(b0));
          asm("v_permlane32_swap_b32 %0, %1" : "+v"(a1), "+v"(b1));
          fw[qg][fi] = u32x4{a0, a1, b0, b1};
        }
      }

      // O += P V (vf loaded in dt-halves); osum += P * ones
#pragma unroll
      for (int dt = 0; dt < 2; ++dt) {
        bf16x8 vf4[4];
#pragma unroll
        for (int ks = 0; ks < 4; ++ks)
          vf4[ks] = *reinterpret_cast<const bf16x8*>(sub + 4096 + (dt * 4 + ks) * 512 + lane * 8);
        __builtin_amdgcn_s_setprio(1);
#pragma unroll
        for (int ks = 0; ks < 4; ++ks) {
          o[0][dt] = mfma32(__builtin_bit_cast(bf16x8, fw[0][ks]), vf4[ks], o[0][dt]);
          o[1][dt] = mfma32(__builtin_bit_cast(bf16x8, fw[1][ks]), vf4[ks], o[1][dt]);
        }
        __builtin_amdgcn_s_setprio(0);
      }
      __builtin_amdgcn_s_setprio(1);
#pragma unroll
      for (int ks = 0; ks < 4; ++ks) {
        osum[0] = mfma32(__builtin_bit_cast(bf16x8, fw[0][ks]), onesf, osum[0]);
        osum[1] = mfma32(__builtin_bit_cast(bf16x8, fw[1][ks]), onesf, osum[1]);
      }
      __builtin_amdgcn_s_setprio(0);
    }

    if (bt + 1 < 16) {
      asm volatile("s_waitcnt vmcnt(0)" ::: "memory");
      __builtin_amdgcn_s_barrier();
      __builtin_amdgcn_sched_barrier(0);
    }
  }

  // normalize + store
#pragma unroll
  for (int qg = 0; qg < 2; ++qg) {
    bf16* obase = att + ((size_t)b * S + q0 + qg * 32) * U + h * DH + l31;
#pragma unroll
    for (int r = 0; r < 16; ++r) {
      const int row = (r & 3) + 8 * (r >> 2) + 4 * hi8;
      const float lr = 1.f / osum[qg][r];
      obase[(size_t)row * U]      = (bf16)(o[qg][0][r] * lr);
      obase[(size_t)row * U + 32] = (bf16)(o[qg][1][r] * lr);
    }
  }
}

// ---------- epilogue: x = relu(att + vres); LayerNorm(x)*gamma + beta ----------
__global__ __launch_bounds__(256) void ln_kernel(
    const bf16* __restrict__ att, const bf16* __restrict__ vres,
    const float* __restrict__ gamma, const float* __restrict__ beta,
    float* __restrict__ out) {
  const int w = threadIdx.x >> 6, lane = threadIdx.x & 63;
  const int row = blockIdx.x * 4 + w;
  const int c0 = lane * 16;
  const bf16* ar = att  + (size_t)row * U + c0;
  const bf16* vr = vres + (size_t)row * U + c0;

  const bf16x8 a0 = *reinterpret_cast<const bf16x8*>(ar);
  const bf16x8 a1 = *reinterpret_cast<const bf16x8*>(ar + 8);
  const bf16x8 v0 = *reinterpret_cast<const bf16x8*>(vr);
  const bf16x8 v1 = *reinterpret_cast<const bf16x8*>(vr + 8);

  float x[16];
  float sum = 0.f, sq = 0.f;
#pragma unroll
  for (int i = 0; i < 8; ++i) {
    x[i]     = fmaxf((float)a0[i] + (float)v0[i], 0.f);
    x[8 + i] = fmaxf((float)a1[i] + (float)v1[i], 0.f);
  }
#pragma unroll
  for (int i = 0; i < 16; ++i) { sum += x[i]; sq += x[i] * x[i]; }
#pragma unroll
  for (int mm = 1; mm < 64; mm <<= 1) {
    sum += __shfl_xor(sum, mm);
    sq  += __shfl_xor(sq, mm);
  }
  const float mean = sum * (1.f / U);
  float var = sq * (1.f / U) - mean * mean;
  var = fmaxf(var, 0.f);
  const float inv = rsqrtf(var + 1e-8f);

  float* orow = out + (size_t)row * U + c0;
#pragma unroll
  for (int j = 0; j < 4; ++j) {
    const float4 g = *reinterpret_cast<const float4*>(gamma + c0 + j * 4);
    const float4 bt = *reinterpret_cast<const float4*>(beta + c0 + j * 4);
    float4 o;
    o.x = g.x * ((x[j * 4 + 0] - mean) * inv) + bt.x;
    o.y = g.y * ((x[j * 4 + 1] - mean) * inv) + bt.y;
    o.z = g.z * ((x[j * 4 + 2] - mean) * inv) + bt.z;
    o.w = g.w * ((x[j * 4 + 3] - mean) * inv) + bt.w;
    *reinterpret_cast<float4*>(orow + j * 4) = o;
  }
}

extern "C" void kernel_launch(void* const* d_in, const int* in_sizes, int n_in,
                              void* d_out, int out_size, void* d_ws, size_t ws_size,
                              hipStream_t stream) {
  const float* queries = (const float*)d_in[0];
  const float* keys    = (const float*)d_in[1];
  const float* values  = (const float*)d_in[2];
  const float* Wq = (const float*)d_in[3];
  const float* bq = (const float*)d_in[4];
  const float* Wk = (const float*)d_in[5];
  const float* bk = (const float*)d_in[6];
  const float* Wv = (const float*)d_in[7];
  const float* bv = (const float*)d_in[8];
  const float* Wr = (const float*)d_in[9];
  const float* br = (const float*)d_in[10];
  const float* gamma = (const float*)d_in[11];
  const float* beta  = (const float*)d_in[12];
  float* out = (float*)d_out;

  char* ws = (char*)d_ws;
  const size_t MB = 1024 * 1024;
  bf16* wqt  = (bf16*)(ws + 0 * MB);
  bf16* wkt  = (bf16*)(ws + 2 * MB);
  bf16* wvt  = (bf16*)(ws + 4 * MB);
  bf16* wrt  = (bf16*)(ws + 6 * MB);
  bf16* Qcvt = (bf16*)(ws + 8 * MB);    // dead after gemm -> attb aliases
  bf16* Kcvt = (bf16*)(ws + 24 * MB);   // dead after gemm -> Rb aliases (Rb written by gemm z=3)
  bf16* Vcvt = (bf16*)(ws + 40 * MB);
  bf16* Qb   = (bf16*)(ws + 56 * MB);
  bf16* Kp   = (bf16*)(ws + 72 * MB);
  bf16* Vp   = (bf16*)(ws + 88 * MB);   // total 104 MB
  bf16* attb = Qcvt;
  bf16* Rb   = Kcvt;

  prep_kernel<<<dim3(16384), 256, 0, stream>>>(
      queries, keys, values, Qcvt, Kcvt, Vcvt,
      Wq, Wk, Wv, Wr, wqt, wkt, wvt, wrt);
  gemm4_kernel<<<dim3(512), 512, 0, stream>>>(
      Qcvt, Kcvt, Vcvt, wqt, wkt, wvt, wrt, bq, bk, bv, br, Qb, Kp, Vp, Rb);
  attn_kernel<<<dim3(512), 256, 0, stream>>>(Qb, Kp, Vp, attb);
  ln_kernel<<<dim3(MTOT / 4), 256, 0, stream>>>(attb, Rb, gamma, beta, out);
}